// Round 2
// baseline (424.886 us; speedup 1.0000x reference)
//
#include <hip/hip_runtime.h>
#include <hip/hip_bf16.h>

#define B_ 8
#define S_ 1024
#define DIN 1024
#define HEADS 16
#define FILTERS 64
#define HF 1024

typedef __attribute__((ext_vector_type(8))) short bf16x8;
typedef __attribute__((ext_vector_type(4))) float f32x4;

__device__ __forceinline__ unsigned short f2bf(float f) {
  unsigned int u = __float_as_uint(f);
  u += 0x7fff + ((u >> 16) & 1);   // round-to-nearest-even
  return (unsigned short)(u >> 16);
}
__device__ __forceinline__ float bf2f(unsigned short h) {
  return __uint_as_float(((unsigned int)h) << 16);
}
__device__ __forceinline__ void gl_lds16(const void* g, void* l) {
  __builtin_amdgcn_global_load_lds(
      (const __attribute__((address_space(1))) unsigned int*)g,
      (__attribute__((address_space(3))) unsigned int*)l, 16, 0, 0);
}

// ---------------------------------------------------------------- fp32 -> bf16 A convert
__global__ __launch_bounds__(256) void convert_a(
    const float* __restrict__ q, const float* __restrict__ k,
    const float* __restrict__ v, unsigned short* __restrict__ out) {
  int z = blockIdx.y;
  const float* src = z == 0 ? q : (z == 1 ? k : v);
  unsigned short* dst = out + (size_t)z * 8388608;
  int i = blockIdx.x * 256 + threadIdx.x;
  #pragma unroll
  for (int u = 0; u < 4; ++u) {
    int idx = i + u * 524288;
    float4 x = ((const float4*)src)[idx];
    ushort4 h = {f2bf(x.x), f2bf(x.y), f2bf(x.z), f2bf(x.w)};
    ((ushort4*)dst)[idx] = h;
  }
}

// ---------------------------------------------------------------- prep
// WT[z][n][k] = W_z[k][n] as bf16 ; W1fT[f][c] = W1[c][f] + (c%64==f)
__global__ __launch_bounds__(256) void prep_weights(
    const float* __restrict__ Wq, const float* __restrict__ Wk,
    const float* __restrict__ Wv, const float* __restrict__ W1,
    unsigned short* __restrict__ WT, unsigned short* __restrict__ W1fT) {
  __shared__ float tl[64][65];
  int t = threadIdx.x;
  int z = blockIdx.y;
  if (z < 3) {
    const float* W = z == 0 ? Wq : (z == 1 ? Wk : Wv);
    unsigned short* out = WT + (size_t)z * 1024 * 1024;
    int k0 = (blockIdx.x >> 4) << 6;
    int n0 = (blockIdx.x & 15) << 6;
    for (int i = 0; i < 16; ++i) {
      int idx = t + i * 256; int r = idx >> 6, c = idx & 63;
      tl[r][c] = W[(size_t)(k0 + r) * HF + n0 + c];
    }
    __syncthreads();
    for (int i = 0; i < 16; ++i) {
      int idx = t + i * 256; int r = idx >> 6, c = idx & 63;
      out[(size_t)(n0 + r) * DIN + k0 + c] = f2bf(tl[c][r]);
    }
  } else {
    if (blockIdx.x >= 16) return;
    int k0 = blockIdx.x << 6;
    for (int i = 0; i < 16; ++i) {
      int idx = t + i * 256; int r = idx >> 6, c = idx & 63;
      tl[r][c] = W1[(size_t)(k0 + r) * FILTERS + c];
    }
    __syncthreads();
    for (int i = 0; i < 16; ++i) {
      int idx = t + i * 256; int f = idx >> 6, c = idx & 63;
      float v = tl[c][f] + ((((k0 + c) & 63) == f) ? 1.0f : 0.0f);
      W1fT[(size_t)f * HF + k0 + c] = f2bf(v);
    }
  }
}

// ---------------------------------------------------------------- QKV GEMM (m97-style)
// A bf16 [8192][1024]; out [B][H][S][F] bf16; K (z==1) pre-scaled by 0.125*log2(e)
__global__ __launch_bounds__(256) void qkv_gemm(
    const unsigned short* __restrict__ Abf, const unsigned short* __restrict__ WT,
    const float* __restrict__ bq, const float* __restrict__ bk,
    const float* __restrict__ bv, unsigned short* __restrict__ outq) {
  __shared__ char lsA[16384];   // [128][64] bf16, linear (global_load_lds)
  __shared__ char lsB[16384];
  int tid = threadIdx.x;
  // XCD-chunked swizzle: per XCD a contiguous run of (z,bm,bn) with bn fastest
  int v = (blockIdx.x & 7) * 192 + (blockIdx.x >> 3);
  int z = v >> 9; int r2 = v & 511; int bm = r2 >> 3; int bn = r2 & 7;
  const unsigned short* A = Abf + (size_t)z * 8388608;
  const float* bias = z == 0 ? bq : (z == 1 ? bk : bv);
  const unsigned short* Bm = WT + (size_t)z * 1048576;
  unsigned short* out = outq + (size_t)z * 8388608;
  int lane = tid & 63, wv = tid >> 6;
  int wr = wv >> 1, wc = wv & 1;
  f32x4 acc[4][4] = {};
  for (int k0 = 0; k0 < DIN; k0 += 64) {
    __syncthreads();
    #pragma unroll
    for (int i = 0; i < 4; ++i) {
      int idx = tid + i * 256;
      int row = idx >> 3, c8 = idx & 7;
      gl_lds16(A + (size_t)(bm * 128 + row) * DIN + k0 + c8 * 8, lsA + idx * 16);
      gl_lds16(Bm + (size_t)(bn * 128 + row) * DIN + k0 + c8 * 8, lsB + idx * 16);
    }
    __syncthreads();   // compiler drains vmcnt before barrier
    #pragma unroll
    for (int kk = 0; kk < 2; ++kk) {
      int cb = kk * 64 + ((lane >> 4) << 4);
      bf16x8 af[4], bfr[4];
      #pragma unroll
      for (int m = 0; m < 4; ++m)
        af[m] = *(const bf16x8*)(lsA + (wr * 64 + m * 16 + (lane & 15)) * 128 + cb);
      #pragma unroll
      for (int n = 0; n < 4; ++n)
        bfr[n] = *(const bf16x8*)(lsB + (wc * 64 + n * 16 + (lane & 15)) * 128 + cb);
      #pragma unroll
      for (int m = 0; m < 4; ++m)
        #pragma unroll
        for (int n = 0; n < 4; ++n)
          acc[m][n] = __builtin_amdgcn_mfma_f32_16x16x32_bf16(af[m], bfr[n], acc[m][n], 0, 0, 0);
    }
  }
  float mul = (z == 1) ? 0.18033688011112042f : 1.0f;  // 0.125*log2(e) folded into K
  #pragma unroll
  for (int n = 0; n < 4; ++n) {
    int col = bn * 128 + wc * 64 + n * 16 + (lane & 15);
    float bb = bias[col];
    int h = col >> 6, f = col & 63;
    #pragma unroll
    for (int m = 0; m < 4; ++m)
      #pragma unroll
      for (int r = 0; r < 4; ++r) {
        int rowg = bm * 128 + wr * 64 + m * 16 + ((lane >> 4) << 2) + r;
        int b = rowg >> 10, s = rowg & 1023;
        out[(size_t)(((b * HEADS + h) << 10) + s) * 64 + f] = f2bf((acc[m][n][r] + bb) * mul);
      }
  }
}

// ---------------------------------------------------------------- V transpose
__global__ __launch_bounds__(256) void transpose_v(
    const unsigned short* __restrict__ v_bh, unsigned short* __restrict__ vT_bh) {
  __shared__ unsigned short tl[64][68];
  int t = threadIdx.x;
  int bh = blockIdx.y;
  int s0 = blockIdx.x << 6;
  const unsigned short* src = v_bh + ((size_t)bh * S_ + s0) * 64;
  #pragma unroll
  for (int i = 0; i < 2; ++i) {
    int idx = t + i * 256; int row = idx >> 3, c8 = idx & 7;
    int4 v = *(const int4*)(src + row * 64 + c8 * 8);
    const unsigned short* pv = (const unsigned short*)&v;
    #pragma unroll
    for (int e = 0; e < 8; ++e) tl[row][c8 * 8 + e] = pv[e];
  }
  __syncthreads();
  unsigned short* dst = vT_bh + (size_t)bh * 64 * S_;
  #pragma unroll
  for (int i = 0; i < 16; ++i) {
    int idx = t + i * 256; int f = idx >> 6, sl = idx & 63;
    dst[(size_t)f * S_ + s0 + sl] = tl[sl][f];
  }
}

// ---------------------------------------------------------------- attention
// no-max softmax (K pre-scaled by 0.125*log2e, scores bounded ~|6|), dbuf K/V,
// async-stage split, 1 barrier/tile, wave-local P, deferred l-reduction.
__global__ __launch_bounds__(256) void attn_kernel(
    const unsigned short* __restrict__ q_bh, const unsigned short* __restrict__ k_bh,
    const unsigned short* __restrict__ vT_bh, unsigned short* __restrict__ en_f) {
  __shared__ char lsQ[8192];
  __shared__ char lsK[2][8192];
  __shared__ char lsV[2][8192];
  __shared__ char lsP[4][2048];
  int tid = threadIdx.x, lane = tid & 63, wv = tid >> 6;
  // XCD swizzle: 16 bh per XCD; tiles of one bh contiguous in dispatch order
  int id = blockIdx.x;
  int bh = ((id & 7) << 4) | ((id >> 3) >> 4);
  int tile = (id >> 3) & 15;
  int b = bh >> 4, h = bh & 15;
  int s0 = tile << 6;
  const unsigned short* qp = q_bh + ((size_t)bh * S_ + s0) * 64;
  #pragma unroll
  for (int i = 0; i < 2; ++i) {
    int idx = tid + i * 256; int row = idx >> 3, c8 = idx & 7;
    int4 vq = *(const int4*)(qp + row * 64 + c8 * 8);
    *(int4*)(lsQ + row * 128 + ((c8 * 16) ^ ((row & 7) << 4))) = vq;
  }
  const unsigned short* kp0 = k_bh + (size_t)bh * 65536;
  const unsigned short* vp0 = vT_bh + (size_t)bh * 65536;   // [64 f][1024 s]
  int srow = tid >> 3, sc8 = tid & 7;
  int4 kreg[2], vreg[2];
  #pragma unroll
  for (int i = 0; i < 2; ++i) {
    int rr = srow + i * 32;
    kreg[i] = *(const int4*)(kp0 + (size_t)rr * 64 + sc8 * 8);
    vreg[i] = *(const int4*)(vp0 + (size_t)rr * S_ + sc8 * 8);
  }
  __syncthreads();   // lsQ ready
  bf16x8 qf[2];
  {
    int qrow = wv * 16 + (lane & 15);
    #pragma unroll
    for (int kk = 0; kk < 2; ++kk) {
      int cb = kk * 64 + ((lane >> 4) << 4);
      qf[kk] = *(const bf16x8*)(lsQ + qrow * 128 + (cb ^ ((qrow & 7) << 4)));
    }
  }
  float l_part[4] = {0.f, 0.f, 0.f, 0.f};
  f32x4 oacc[4] = {};
  int cur = 0;
  for (int t = 0; t < 16; ++t) {
    // write tile t (in regs) -> LDS buf[cur] (swizzled)
    #pragma unroll
    for (int i = 0; i < 2; ++i) {
      int rr = srow + i * 32;
      int off = rr * 128 + ((sc8 * 16) ^ ((rr & 7) << 4));
      *(int4*)(lsK[cur] + off) = kreg[i];
      *(int4*)(lsV[cur] + off) = vreg[i];
    }
    // issue loads for t+1 (latency hides under compute below)
    if (t < 15) {
      #pragma unroll
      for (int i = 0; i < 2; ++i) {
        int rr = srow + i * 32;
        kreg[i] = *(const int4*)(kp0 + (size_t)((t + 1) * 64 + rr) * 64 + sc8 * 8);
        vreg[i] = *(const int4*)(vp0 + (size_t)rr * S_ + (t + 1) * 64 + sc8 * 8);
      }
    }
    __syncthreads();   // buf[cur] visible to all waves
    // QK^T
    f32x4 sacc[4] = {};
    __builtin_amdgcn_s_setprio(1);
    #pragma unroll
    for (int kk = 0; kk < 2; ++kk) {
      int cb = kk * 64 + ((lane >> 4) << 4);
      #pragma unroll
      for (int j = 0; j < 4; ++j) {
        int rr = j * 16 + (lane & 15);
        bf16x8 kf = *(const bf16x8*)(lsK[cur] + rr * 128 + (cb ^ ((rr & 7) << 4)));
        sacc[j] = __builtin_amdgcn_mfma_f32_16x16x32_bf16(qf[kk], kf, sacc[j], 0, 0, 0);
      }
    }
    __builtin_amdgcn_s_setprio(0);
    // P = exp2(s'), accumulate partial l, wave-local P -> LDS
    char* pbase = lsP[wv];
    #pragma unroll
    for (int j = 0; j < 4; ++j)
      #pragma unroll
      for (int r = 0; r < 4; ++r) {
        float p = exp2f(sacc[j][r]);
        l_part[r] += p;
        int prow = ((lane >> 4) << 2) + r;
        int cb = (j * 32 + ((lane & 15) << 1)) ^ ((prow & 7) << 4);
        *(unsigned short*)(pbase + prow * 128 + cb) = f2bf(p);
      }
    // PV (wave-local P read; compiler orders via lgkmcnt)
    __builtin_amdgcn_s_setprio(1);
    #pragma unroll
    for (int kk = 0; kk < 2; ++kk) {
      int cb = kk * 64 + ((lane >> 4) << 4);
      int prow = lane & 15;
      bf16x8 pa = *(const bf16x8*)(pbase + prow * 128 + (cb ^ ((prow & 7) << 4)));
      #pragma unroll
      for (int j = 0; j < 4; ++j) {
        int rr = j * 16 + (lane & 15);
        bf16x8 vf = *(const bf16x8*)(lsV[cur] + rr * 128 + (cb ^ ((rr & 7) << 4)));
        oacc[j] = __builtin_amdgcn_mfma_f32_16x16x32_bf16(pa, vf, oacc[j], 0, 0, 0);
      }
    }
    __builtin_amdgcn_s_setprio(0);
    cur ^= 1;
  }
  // epilogue: one l-reduction, normalize, +q residual, bf16 out
  #pragma unroll
  for (int r = 0; r < 4; ++r) {
    float l = l_part[r];
    l += __shfl_xor(l, 1); l += __shfl_xor(l, 2);
    l += __shfl_xor(l, 4); l += __shfl_xor(l, 8);
    float inv = 1.0f / l;
    int qrow = wv * 16 + ((lane >> 4) << 2) + r;
    int s = s0 + qrow;
    unsigned short* op = en_f + ((size_t)(b * S_ + s)) * HF + h * 64;
    #pragma unroll
    for (int j = 0; j < 4; ++j) {
      int cb = ((j * 32 + ((lane & 15) << 1)) ^ ((qrow & 7) << 4));
      float qv = bf2f(*(const unsigned short*)(lsQ + qrow * 128 + cb));
      op[j * 16 + (lane & 15)] = f2bf(oacc[j][r] * inv + qv);
    }
  }
}

// ---------------------------------------------------------------- GroupNorm1 (bf16 en_f)
__global__ __launch_bounds__(256) void gn1_stats(
    const unsigned short* __restrict__ en_f, float* __restrict__ gsum, float* __restrict__ gss) {
  int b = blockIdx.x >> 2;
  int c = ((blockIdx.x & 3) << 8) + threadIdx.x;
  int s0 = blockIdx.y << 7;
  float sum = 0.f, ss = 0.f;
  const unsigned short* p = en_f + ((size_t)(b << 10) + s0) * 1024 + c;
  for (int i = 0; i < 128; ++i) {
    float x = bf2f(p[(size_t)i * 1024]);
    sum += x; ss += x * x;
  }
  atomicAdd(&gsum[b * 1024 + c], sum);
  atomicAdd(&gss[b * 1024 + c], ss);
}

__global__ __launch_bounds__(256) void gn1_norm(
    const unsigned short* __restrict__ en_f, const float* __restrict__ gsum,
    const float* __restrict__ gss, unsigned short* __restrict__ enf0) {
  const float invS = 1.0f / 1024.0f;
  int gs = gridDim.x * blockDim.x;
  for (size_t i = (size_t)blockIdx.x * 256 + threadIdx.x; i < (size_t)2097152; i += gs) {
    ushort4 x = ((const ushort4*)en_f)[i];
    size_t lin = i * 4;
    int c = (int)(lin & 1023);
    int b = (int)(lin >> 20);
    unsigned short xs[4] = {x.x, x.y, x.z, x.w};
    unsigned short o[4];
    #pragma unroll
    for (int e = 0; e < 4; ++e) {
      float mean = gsum[b * 1024 + c + e] * invS;
      float var = gss[b * 1024 + c + e] * invS - mean * mean;
      float rstd = rsqrtf(var + 1e-3f);
      o[e] = f2bf((bf2f(xs[e]) - mean) * rstd);
    }
    ushort4 y = {o[0], o[1], o[2], o[3]};
    ((ushort4*)enf0)[i] = y;
  }
}

// ---------------------------------------------------------------- dense (+folded head-sum)
__global__ __launch_bounds__(256) void dense_kernel(
    const unsigned short* __restrict__ enf0, const unsigned short* __restrict__ W1fT,
    const float* __restrict__ b1, float* __restrict__ out1) {
  __shared__ char lsA[64 * 128], lsB[64 * 128];
  int tid = threadIdx.x, lane = tid & 63, wv = tid >> 6;
  int bm = blockIdx.x;
  f32x4 acc[4] = {};
  for (int k0 = 0; k0 < HF; k0 += 64) {
    __syncthreads();
    #pragma unroll
    for (int i = 0; i < 2; ++i) {
      int idx = tid + i * 256; int row = idx >> 3, c8 = idx & 7;
      int4 v = *(const int4*)(enf0 + (size_t)(bm * 64 + row) * HF + k0 + c8 * 8);
      *(int4*)(lsA + row * 128 + ((c8 * 16) ^ ((row & 7) << 4))) = v;
    }
    #pragma unroll
    for (int i = 0; i < 2; ++i) {
      int idx = tid + i * 256; int row = idx >> 3, c8 = idx & 7;
      int4 v = *(const int4*)(W1fT + (size_t)row * HF + k0 + c8 * 8);
      *(int4*)(lsB + row * 128 + ((c8 * 16) ^ ((row & 7) << 4))) = v;
    }
    __syncthreads();
    #pragma unroll
    for (int kk = 0; kk < 2; ++kk) {
      int cb = kk * 64 + ((lane >> 4) << 4);
      int arow = wv * 16 + (lane & 15);
      bf16x8 af = *(const bf16x8*)(lsA + arow * 128 + (cb ^ ((arow & 7) << 4)));
      #pragma unroll
      for (int j = 0; j < 4; ++j) {
        int row = j * 16 + (lane & 15);
        bf16x8 bfr = *(const bf16x8*)(lsB + row * 128 + (cb ^ ((row & 7) << 4)));
        acc[j] = __builtin_amdgcn_mfma_f32_16x16x32_bf16(af, bfr, acc[j], 0, 0, 0);
      }
    }
  }
  #pragma unroll
  for (int j = 0; j < 4; ++j) {
    int f = j * 16 + (lane & 15);
    float bb = b1[f];
    #pragma unroll
    for (int r = 0; r < 4; ++r) {
      int rowg = bm * 64 + wv * 16 + ((lane >> 4) << 2) + r;
      out1[(size_t)rowg * 64 + f] = acc[j][r] + bb;
    }
  }
}

// ---------------------------------------------------------------- GroupNorm2
__global__ __launch_bounds__(256) void gn2_stats(
    const float* __restrict__ out1, float* __restrict__ g2sum, float* __restrict__ g2ss) {
  __shared__ float r1[256], r2[256];
  int t = threadIdx.x;
  int b = blockIdx.y;
  int s0 = blockIdx.x << 6;
  int f = t & 63, sl = t >> 6;
  float sum = 0.f, ss = 0.f;
  for (int i = 0; i < 16; ++i) {
    int s = s0 + sl + i * 4;
    float x = out1[((size_t)(b << 10) + s) * 64 + f];
    sum += x; ss += x * x;
  }
  r1[t] = sum; r2[t] = ss;
  __syncthreads();
  if (t < 64) {
    sum = r1[t] + r1[t + 64] + r1[t + 128] + r1[t + 192];
    ss  = r2[t] + r2[t + 64] + r2[t + 128] + r2[t + 192];
    atomicAdd(&g2sum[b * 64 + t], sum);
    atomicAdd(&g2ss[b * 64 + t], ss);
  }
}

__global__ __launch_bounds__(256) void gn2_norm(
    const float* __restrict__ out1, const float* __restrict__ g2sum,
    const float* __restrict__ g2ss, float* __restrict__ dout) {
  const float invS = 1.0f / 1024.0f;
  int gs = gridDim.x * blockDim.x;
  for (int i = blockIdx.x * 256 + threadIdx.x; i < 131072; i += gs) {
    float4 x = ((const float4*)out1)[i];
    int lin = i * 4;
    int f = lin & 63;
    int b = lin >> 16;
    float vals[4] = {x.x, x.y, x.z, x.w};
    float o[4];
    #pragma unroll
    for (int e = 0; e < 4; ++e) {
      float mean = g2sum[b * 64 + f + e] * invS;
      float var = g2ss[b * 64 + f + e] * invS - mean * mean;
      float rstd = rsqrtf(var + 1e-3f);
      o[e] = (vals[e] - mean) * rstd;
    }
    float4 y = {o[0], o[1], o[2], o[3]};
    ((float4*)dout)[i] = y;
  }
}

// ---------------------------------------------------------------- launch
extern "C" void kernel_launch(void* const* d_in, const int* in_sizes, int n_in,
                              void* d_out, int out_size, void* d_ws, size_t ws_size,
                              hipStream_t stream) {
  const float* qw = (const float*)d_in[0];
  const float* kw = (const float*)d_in[1];
  const float* vw = (const float*)d_in[2];
  const float* Wq = (const float*)d_in[3];
  const float* bq = (const float*)d_in[4];
  const float* Wk = (const float*)d_in[5];
  const float* bk = (const float*)d_in[6];
  const float* Wv = (const float*)d_in[7];
  const float* bv = (const float*)d_in[8];
  const float* W1 = (const float*)d_in[9];
  const float* b1 = (const float*)d_in[10];

  char* ws = (char*)d_ws;
  unsigned short* WT   = (unsigned short*)(ws);                   // 6 MB
  unsigned short* W1fT = (unsigned short*)(ws + 6291456);         // 128 KB
  unsigned short* qb   = (unsigned short*)(ws + 6422528);         // q,k,v: 3 x 16 MB bf16
  unsigned short* vT   = (unsigned short*)(ws + 56754176);        // 16 MB
  unsigned short* Abf  = (unsigned short*)(ws + 73531392);        // 48 MB (dead after qkv_gemm)
  unsigned short* en_f = (unsigned short*)(ws + 73531392);        // 16 MB bf16 (aliases Abf)
  unsigned short* enf0 = (unsigned short*)(ws + 90308608);        // 16 MB bf16
  float* out1          = (float*)(ws + 107085824);                // 2 MB
  float* gsum          = (float*)(ws + 123863040);                // 32 KB
  float* gss           = (float*)(ws + 123895808);                // 32 KB
  float* g2sum         = (float*)(ws + 123928576);                // 2 KB
  float* g2ss          = (float*)(ws + 123930624);                // 2 KB

  hipMemsetAsync(gsum, 0, 65536, stream);   // gsum + gss
  hipMemsetAsync(g2sum, 0, 4096, stream);   // g2sum + g2ss

  convert_a<<<dim3(2048, 3), 256, 0, stream>>>(qw, kw, vw, Abf);
  prep_weights<<<dim3(256, 4), 256, 0, stream>>>(Wq, Wk, Wv, W1, WT, W1fT);
  qkv_gemm<<<1536, 256, 0, stream>>>(Abf, WT, bq, bk, bv, qb);
  transpose_v<<<dim3(16, 128), 256, 0, stream>>>(qb + 2 * 8388608, vT);
  attn_kernel<<<2048, 256, 0, stream>>>(qb, qb + 8388608, vT, en_f);
  gn1_stats<<<dim3(32, 8), 256, 0, stream>>>(en_f, gsum, gss);
  gn1_norm<<<2048, 256, 0, stream>>>(en_f, gsum, gss, enf0);
  dense_kernel<<<128, 256, 0, stream>>>(enf0, W1fT, b1, out1);
  gn2_stats<<<dim3(16, 8), 256, 0, stream>>>(out1, g2sum, g2ss);
  gn2_norm<<<512, 256, 0, stream>>>(out1, g2sum, g2ss, (float*)d_out);
}

// Round 3
// 323.521 us; speedup vs baseline: 1.3133x; 1.3133x over previous
//
#include <hip/hip_runtime.h>
#include <hip/hip_bf16.h>

#define B_ 8
#define S_ 1024
#define DIN 1024
#define HEADS 16
#define FILTERS 64
#define HF 1024

typedef __attribute__((ext_vector_type(8))) short bf16x8;
typedef __attribute__((ext_vector_type(4))) float f32x4;
typedef __attribute__((ext_vector_type(16))) float f32x16;
typedef __attribute__((ext_vector_type(4))) unsigned int u32x4;

__device__ __forceinline__ unsigned short f2bf(float f) {
  unsigned int u = __float_as_uint(f);
  u += 0x7fff + ((u >> 16) & 1);   // round-to-nearest-even
  return (unsigned short)(u >> 16);
}
__device__ __forceinline__ float bf2f(unsigned short h) {
  return __uint_as_float(((unsigned int)h) << 16);
}
__device__ __forceinline__ void gl_lds16(const void* g, void* l) {
  __builtin_amdgcn_global_load_lds(
      (const __attribute__((address_space(1))) unsigned int*)g,
      (__attribute__((address_space(3))) unsigned int*)l, 16, 0, 0);
}

// ---------------------------------------------------------------- fp32 -> bf16 A convert
__global__ __launch_bounds__(256) void convert_a(
    const float* __restrict__ q, const float* __restrict__ k,
    const float* __restrict__ v, unsigned short* __restrict__ out) {
  int z = blockIdx.y;
  const float* src = z == 0 ? q : (z == 1 ? k : v);
  unsigned short* dst = out + (size_t)z * 8388608;
  int i = blockIdx.x * 256 + threadIdx.x;
  #pragma unroll
  for (int u = 0; u < 4; ++u) {
    int idx = i + u * 524288;
    float4 x = ((const float4*)src)[idx];
    ushort4 h = {f2bf(x.x), f2bf(x.y), f2bf(x.z), f2bf(x.w)};
    ((ushort4*)dst)[idx] = h;
  }
}

// ---------------------------------------------------------------- prep
// WT[z][n][k] = W_z[k][n] as bf16 ; W1fT[f][c] = W1[c][f] + (c%64==f)
__global__ __launch_bounds__(256) void prep_weights(
    const float* __restrict__ Wq, const float* __restrict__ Wk,
    const float* __restrict__ Wv, const float* __restrict__ W1,
    unsigned short* __restrict__ WT, unsigned short* __restrict__ W1fT) {
  __shared__ float tl[64][65];
  int t = threadIdx.x;
  int z = blockIdx.y;
  if (z < 3) {
    const float* W = z == 0 ? Wq : (z == 1 ? Wk : Wv);
    unsigned short* out = WT + (size_t)z * 1024 * 1024;
    int k0 = (blockIdx.x >> 4) << 6;
    int n0 = (blockIdx.x & 15) << 6;
    for (int i = 0; i < 16; ++i) {
      int idx = t + i * 256; int r = idx >> 6, c = idx & 63;
      tl[r][c] = W[(size_t)(k0 + r) * HF + n0 + c];
    }
    __syncthreads();
    for (int i = 0; i < 16; ++i) {
      int idx = t + i * 256; int r = idx >> 6, c = idx & 63;
      out[(size_t)(n0 + r) * DIN + k0 + c] = f2bf(tl[c][r]);
    }
  } else {
    if (blockIdx.x >= 16) return;
    int k0 = blockIdx.x << 6;
    for (int i = 0; i < 16; ++i) {
      int idx = t + i * 256; int r = idx >> 6, c = idx & 63;
      tl[r][c] = W1[(size_t)(k0 + r) * FILTERS + c];
    }
    __syncthreads();
    for (int i = 0; i < 16; ++i) {
      int idx = t + i * 256; int f = idx >> 6, c = idx & 63;
      float v = tl[c][f] + ((((k0 + c) & 63) == f) ? 1.0f : 0.0f);
      W1fT[(size_t)f * HF + k0 + c] = f2bf(v);
    }
  }
}

// ---------------------------------------------------------------- QKV GEMM (m97-style)
__global__ __launch_bounds__(256) void qkv_gemm(
    const unsigned short* __restrict__ Abf, const unsigned short* __restrict__ WT,
    const float* __restrict__ bq, const float* __restrict__ bk,
    const float* __restrict__ bv, unsigned short* __restrict__ outq) {
  __shared__ char lsA[16384];   // [128][64] bf16, linear (global_load_lds)
  __shared__ char lsB[16384];
  int tid = threadIdx.x;
  int v = (blockIdx.x & 7) * 192 + (blockIdx.x >> 3);
  int z = v >> 9; int r2 = v & 511; int bm = r2 >> 3; int bn = r2 & 7;
  const unsigned short* A = Abf + (size_t)z * 8388608;
  const float* bias = z == 0 ? bq : (z == 1 ? bk : bv);
  const unsigned short* Bm = WT + (size_t)z * 1048576;
  unsigned short* out = outq + (size_t)z * 8388608;
  int lane = tid & 63, wv = tid >> 6;
  int wr = wv >> 1, wc = wv & 1;
  f32x4 acc[4][4] = {};
  for (int k0 = 0; k0 < DIN; k0 += 64) {
    __syncthreads();
    #pragma unroll
    for (int i = 0; i < 4; ++i) {
      int idx = tid + i * 256;
      int row = idx >> 3, c8 = idx & 7;
      gl_lds16(A + (size_t)(bm * 128 + row) * DIN + k0 + c8 * 8, lsA + idx * 16);
      gl_lds16(Bm + (size_t)(bn * 128 + row) * DIN + k0 + c8 * 8, lsB + idx * 16);
    }
    __syncthreads();
    #pragma unroll
    for (int kk = 0; kk < 2; ++kk) {
      int cb = kk * 64 + ((lane >> 4) << 4);
      bf16x8 af[4], bfr[4];
      #pragma unroll
      for (int m = 0; m < 4; ++m)
        af[m] = *(const bf16x8*)(lsA + (wr * 64 + m * 16 + (lane & 15)) * 128 + cb);
      #pragma unroll
      for (int n = 0; n < 4; ++n)
        bfr[n] = *(const bf16x8*)(lsB + (wc * 64 + n * 16 + (lane & 15)) * 128 + cb);
      #pragma unroll
      for (int m = 0; m < 4; ++m)
        #pragma unroll
        for (int n = 0; n < 4; ++n)
          acc[m][n] = __builtin_amdgcn_mfma_f32_16x16x32_bf16(af[m], bfr[n], acc[m][n], 0, 0, 0);
    }
  }
  float mul = (z == 1) ? 0.18033688011112042f : 1.0f;  // 0.125*log2(e) folded into K
  #pragma unroll
  for (int n = 0; n < 4; ++n) {
    int col = bn * 128 + wc * 64 + n * 16 + (lane & 15);
    float bb = bias[col];
    int h = col >> 6, f = col & 63;
    #pragma unroll
    for (int m = 0; m < 4; ++m)
      #pragma unroll
      for (int r = 0; r < 4; ++r) {
        int rowg = bm * 128 + wr * 64 + m * 16 + ((lane >> 4) << 2) + r;
        int b = rowg >> 10, s = rowg & 1023;
        out[(size_t)(((b * HEADS + h) << 10) + s) * 64 + f] = f2bf((acc[m][n][r] + bb) * mul);
      }
  }
}

// ---------------------------------------------------------------- V transpose
__global__ __launch_bounds__(256) void transpose_v(
    const unsigned short* __restrict__ v_bh, unsigned short* __restrict__ vT_bh) {
  __shared__ unsigned short tl[64][68];
  int t = threadIdx.x;
  int bh = blockIdx.y;
  int s0 = blockIdx.x << 6;
  const unsigned short* src = v_bh + ((size_t)bh * S_ + s0) * 64;
  #pragma unroll
  for (int i = 0; i < 2; ++i) {
    int idx = t + i * 256; int row = idx >> 3, c8 = idx & 7;
    int4 v = *(const int4*)(src + row * 64 + c8 * 8);
    const unsigned short* pv = (const unsigned short*)&v;
    #pragma unroll
    for (int e = 0; e < 8; ++e) tl[row][c8 * 8 + e] = pv[e];
  }
  __syncthreads();
  unsigned short* dst = vT_bh + (size_t)bh * 64 * S_;
  #pragma unroll
  for (int i = 0; i < 16; ++i) {
    int idx = t + i * 256; int f = idx >> 6, sl = idx & 63;
    dst[(size_t)f * S_ + s0 + sl] = tl[sl][f];
  }
}

// ---------------------------------------------------------------- attention (m214-style)
// 32x32x16 MFMA, swapped QK^T, in-register softmax via cvt_pk+permlane32_swap,
// Q-frags in regs, K/V dbuf with prefetch before the single per-tile barrier.
__global__ __launch_bounds__(256, 3) void attn_kernel(
    const unsigned short* __restrict__ q_bh, const unsigned short* __restrict__ k_bh,
    const unsigned short* __restrict__ vT_bh, unsigned short* __restrict__ en_f) {
  __shared__ char lsQ[16384];            // [128 q][64 d] swizzled
  __shared__ char lsK[2][8192];          // [64 kpos][64 d]
  __shared__ char lsV[2][8192];          // [64 f][64 kpos]
  __shared__ float lsL[4][32];
  int tid = threadIdx.x, lane = tid & 63, wv = tid >> 6;
  int l31 = lane & 31, hi = lane >> 5;
  int id = blockIdx.x;                   // 1024 = 8 xcd * 16 bh * 8 qt
  int r_ = id >> 3;
  int bh = ((id & 7) << 4) | (r_ >> 3);
  int qt = r_ & 7;
  int b = bh >> 4, h = bh & 15;
  int s0 = qt << 7;                      // 128 q rows per block
  const unsigned short* qp = q_bh + ((size_t)bh * S_ + s0) * 64;
  const unsigned short* kp0 = k_bh + (size_t)bh * 65536;
  const unsigned short* vp0 = vT_bh + (size_t)bh * 65536;   // [64 f][1024 s]

  // stage Q (16KB) + K/V tile 0 (8KB each)
  #pragma unroll
  for (int i = 0; i < 4; ++i) {
    int idx = tid + i * 256; int row = idx >> 3, c8 = idx & 7;
    int4 vq = *(const int4*)(qp + row * 64 + c8 * 8);
    *(int4*)(lsQ + row * 128 + ((c8 * 16) ^ ((row & 7) << 4))) = vq;
  }
  #pragma unroll
  for (int i = 0; i < 2; ++i) {
    int idx = tid + i * 256; int row = idx >> 3, c8 = idx & 7;
    int4 vk = *(const int4*)(kp0 + idx * 8);
    int4 vv = *(const int4*)(vp0 + (size_t)row * S_ + c8 * 8);
    int off = row * 128 + ((c8 * 16) ^ ((row & 7) << 4));
    *(int4*)(lsK[0] + off) = vk;
    *(int4*)(lsV[0] + off) = vv;
  }
  __syncthreads();

  // Q B-frags (hoisted): lane holds Q[q = 32*wv + l31][d = dc*16 + 8*hi + e]
  bf16x8 qf[4];
  int qrow0 = 32 * wv + l31;
  #pragma unroll
  for (int dc = 0; dc < 4; ++dc)
    qf[dc] = *(const bf16x8*)(lsQ + qrow0 * 128 + ((dc * 32 + hi * 16) ^ ((qrow0 & 7) << 4)));

  f32x16 o0 = {}, o1 = {};
  float l_part = 0.f;
  for (int t = 0; t < 16; ++t) {
    char* Kb = lsK[t & 1];
    char* Vb = lsV[t & 1];
    // prefetch tile t+1 into regs (consumed by ds_write below; flies under compute)
    int4 kr[2], vr[2];
    if (t < 15) {
      #pragma unroll
      for (int i = 0; i < 2; ++i) {
        int idx = tid + i * 256; int row = idx >> 3, c8 = idx & 7;
        kr[i] = *(const int4*)(kp0 + (t + 1) * 4096 + idx * 8);
        vr[i] = *(const int4*)(vp0 + (size_t)row * S_ + (t + 1) * 64 + c8 * 8);
      }
    }
    // swapped QK^T: S[kpos][q]; lane = q-col, regs = kpos
    f32x16 sa = {}, sb = {};
    __builtin_amdgcn_s_setprio(1);
    #pragma unroll
    for (int dc = 0; dc < 4; ++dc) {
      int cb = dc * 32 + hi * 16;
      int swz = (l31 & 7) << 4;
      bf16x8 k0 = *(const bf16x8*)(Kb + l31 * 128 + (cb ^ swz));
      bf16x8 k1 = *(const bf16x8*)(Kb + (32 + l31) * 128 + (cb ^ swz));
      sa = __builtin_amdgcn_mfma_f32_32x32x16_bf16(k0, qf[dc], sa, 0, 0, 0);
      sb = __builtin_amdgcn_mfma_f32_32x32x16_bf16(k1, qf[dc], sb, 0, 0, 0);
    }
    __builtin_amdgcn_s_setprio(0);
    // P = exp2(S) in-register (K pre-scaled by 0.125*log2e); partial l
    #pragma unroll
    for (int r = 0; r < 16; ++r) {
      float ea, eb;
      asm("v_exp_f32 %0, %1" : "=v"(ea) : "v"(sa[r]));
      asm("v_exp_f32 %0, %1" : "=v"(eb) : "v"(sb[r]));
      sa[r] = ea; sb[r] = eb;
      l_part += ea + eb;
    }
    // build PV A-frags: chunk c covers kpos 16c..16c+15
    bf16x8 paf[4];
    #pragma unroll
    for (int c = 0; c < 4; ++c) {
      int base = (c & 1) * 8;
      float e0 = (c < 2) ? sa[base + 0] : sb[base + 0];
      float e1 = (c < 2) ? sa[base + 1] : sb[base + 1];
      float e2 = (c < 2) ? sa[base + 2] : sb[base + 2];
      float e3 = (c < 2) ? sa[base + 3] : sb[base + 3];
      float e4 = (c < 2) ? sa[base + 4] : sb[base + 4];
      float e5 = (c < 2) ? sa[base + 5] : sb[base + 5];
      float e6 = (c < 2) ? sa[base + 6] : sb[base + 6];
      float e7 = (c < 2) ? sa[base + 7] : sb[base + 7];
      unsigned int X1, X2, Y1, Y2;
      asm("v_cvt_pk_bf16_f32 %0, %1, %2" : "=v"(X1) : "v"(e0), "v"(e1));
      asm("v_cvt_pk_bf16_f32 %0, %1, %2" : "=v"(X2) : "v"(e2), "v"(e3));
      asm("v_cvt_pk_bf16_f32 %0, %1, %2" : "=v"(Y1) : "v"(e4), "v"(e5));
      asm("v_cvt_pk_bf16_f32 %0, %1, %2" : "=v"(Y2) : "v"(e6), "v"(e7));
      asm("v_permlane32_swap_b32 %0, %1" : "+v"(X1), "+v"(Y1));
      asm("v_permlane32_swap_b32 %0, %1" : "+v"(X2), "+v"(Y2));
      u32x4 w4 = {X1, X2, Y1, Y2};
      paf[c] = __builtin_bit_cast(bf16x8, w4);
    }
    // PV: O[q][f] += P[q][kpos] V[kpos][f]; B from V^T tile rows f
    __builtin_amdgcn_s_setprio(1);
    #pragma unroll
    for (int c = 0; c < 4; ++c) {
      int cb = c * 32 + hi * 16;
      int swz = (l31 & 7) << 4;
      bf16x8 v0 = *(const bf16x8*)(Vb + l31 * 128 + (cb ^ swz));
      bf16x8 v1 = *(const bf16x8*)(Vb + (32 + l31) * 128 + (cb ^ swz));
      o0 = __builtin_amdgcn_mfma_f32_32x32x16_bf16(paf[c], v0, o0, 0, 0, 0);
      o1 = __builtin_amdgcn_mfma_f32_32x32x16_bf16(paf[c], v1, o1, 0, 0, 0);
    }
    __builtin_amdgcn_s_setprio(0);
    // write prefetched tile t+1 (vmcnt satisfied here, then barrier)
    if (t < 15) {
      #pragma unroll
      for (int i = 0; i < 2; ++i) {
        int idx = tid + i * 256; int row = idx >> 3, c8 = idx & 7;
        int off = row * 128 + ((c8 * 16) ^ ((row & 7) << 4));
        *(int4*)(lsK[(t + 1) & 1] + off) = kr[i];
        *(int4*)(lsV[(t + 1) & 1] + off) = vr[i];
      }
    }
    __syncthreads();
  }
  // epilogue: l across lane pairs, normalize, +q residual
  float lf = l_part + __shfl_xor(l_part, 32);
  if (lane < 32) lsL[wv][l31] = lf;
  #pragma unroll
  for (int r = 0; r < 16; ++r) {
    int q = (r & 3) + 8 * (r >> 2) + 4 * hi;
    float linv = 1.0f / lsL[wv][q];
    int qrow = 32 * wv + q;
    int srow = s0 + qrow;
    unsigned short* op = en_f + ((size_t)(b * S_ + srow)) * HF + h * 64;
    int swz = (qrow & 7) << 4;
    float qr0 = bf2f(*(const unsigned short*)(lsQ + qrow * 128 + ((l31 * 2) ^ swz)));
    float qr1 = bf2f(*(const unsigned short*)(lsQ + qrow * 128 + (((32 + l31) * 2) ^ swz)));
    op[l31] = f2bf(o0[r] * linv + qr0);
    op[32 + l31] = f2bf(o1[r] * linv + qr1);
  }
}

// ---------------------------------------------------------------- GroupNorm1 (bf16 en_f)
__global__ __launch_bounds__(256) void gn1_stats(
    const unsigned short* __restrict__ en_f, float* __restrict__ gsum, float* __restrict__ gss) {
  int b = blockIdx.x >> 2;
  int c = ((blockIdx.x & 3) << 8) + threadIdx.x;
  int s0 = blockIdx.y << 7;
  float sum = 0.f, ss = 0.f;
  const unsigned short* p = en_f + ((size_t)(b << 10) + s0) * 1024 + c;
  for (int i = 0; i < 128; ++i) {
    float x = bf2f(p[(size_t)i * 1024]);
    sum += x; ss += x * x;
  }
  atomicAdd(&gsum[b * 1024 + c], sum);
  atomicAdd(&gss[b * 1024 + c], ss);
}

__global__ __launch_bounds__(256) void gn1_norm(
    const unsigned short* __restrict__ en_f, const float* __restrict__ gsum,
    const float* __restrict__ gss, unsigned short* __restrict__ enf0) {
  const float invS = 1.0f / 1024.0f;
  int gs = gridDim.x * blockDim.x;
  for (size_t i = (size_t)blockIdx.x * 256 + threadIdx.x; i < (size_t)2097152; i += gs) {
    ushort4 x = ((const ushort4*)en_f)[i];
    size_t lin = i * 4;
    int c = (int)(lin & 1023);
    int b = (int)(lin >> 20);
    unsigned short xs[4] = {x.x, x.y, x.z, x.w};
    unsigned short o[4];
    #pragma unroll
    for (int e = 0; e < 4; ++e) {
      float mean = gsum[b * 1024 + c + e] * invS;
      float var = gss[b * 1024 + c + e] * invS - mean * mean;
      float rstd = rsqrtf(var + 1e-3f);
      o[e] = f2bf((bf2f(xs[e]) - mean) * rstd);
    }
    ushort4 y = {o[0], o[1], o[2], o[3]};
    ((ushort4*)enf0)[i] = y;
  }
}

// ---------------------------------------------------------------- dense (+folded head-sum)
__global__ __launch_bounds__(256) void dense_kernel(
    const unsigned short* __restrict__ enf0, const unsigned short* __restrict__ W1fT,
    const float* __restrict__ b1, float* __restrict__ out1) {
  __shared__ char lsA[64 * 128], lsB[64 * 128];
  int tid = threadIdx.x, lane = tid & 63, wv = tid >> 6;
  int bm = blockIdx.x;
  f32x4 acc[4] = {};
  for (int k0 = 0; k0 < HF; k0 += 64) {
    __syncthreads();
    #pragma unroll
    for (int i = 0; i < 2; ++i) {
      int idx = tid + i * 256; int row = idx >> 3, c8 = idx & 7;
      int4 v = *(const int4*)(enf0 + (size_t)(bm * 64 + row) * HF + k0 + c8 * 8);
      *(int4*)(lsA + row * 128 + ((c8 * 16) ^ ((row & 7) << 4))) = v;
    }
    #pragma unroll
    for (int i = 0; i < 2; ++i) {
      int idx = tid + i * 256; int row = idx >> 3, c8 = idx & 7;
      int4 v = *(const int4*)(W1fT + (size_t)row * HF + k0 + c8 * 8);
      *(int4*)(lsB + row * 128 + ((c8 * 16) ^ ((row & 7) << 4))) = v;
    }
    __syncthreads();
    #pragma unroll
    for (int kk = 0; kk < 2; ++kk) {
      int cb = kk * 64 + ((lane >> 4) << 4);
      int arow = wv * 16 + (lane & 15);
      bf16x8 af = *(const bf16x8*)(lsA + arow * 128 + (cb ^ ((arow & 7) << 4)));
      #pragma unroll
      for (int j = 0; j < 4; ++j) {
        int row = j * 16 + (lane & 15);
        bf16x8 bfr = *(const bf16x8*)(lsB + row * 128 + (cb ^ ((row & 7) << 4)));
        acc[j] = __builtin_amdgcn_mfma_f32_16x16x32_bf16(af, bfr, acc[j], 0, 0, 0);
      }
    }
  }
  #pragma unroll
  for (int j = 0; j < 4; ++j) {
    int f = j * 16 + (lane & 15);
    float bb = b1[f];
    #pragma unroll
    for (int r = 0; r < 4; ++r) {
      int rowg = bm * 64 + wv * 16 + ((lane >> 4) << 2) + r;
      out1[(size_t)rowg * 64 + f] = acc[j][r] + bb;
    }
  }
}

// ---------------------------------------------------------------- GroupNorm2
__global__ __launch_bounds__(256) void gn2_stats(
    const float* __restrict__ out1, float* __restrict__ g2sum, float* __restrict__ g2ss) {
  __shared__ float r1[256], r2[256];
  int t = threadIdx.x;
  int b = blockIdx.y;
  int s0 = blockIdx.x << 6;
  int f = t & 63, sl = t >> 6;
  float sum = 0.f, ss = 0.f;
  for (int i = 0; i < 16; ++i) {
    int s = s0 + sl + i * 4;
    float x = out1[((size_t)(b << 10) + s) * 64 + f];
    sum += x; ss += x * x;
  }
  r1[t] = sum; r2[t] = ss;
  __syncthreads();
  if (t < 64) {
    sum = r1[t] + r1[t + 64] + r1[t + 128] + r1[t + 192];
    ss  = r2[t] + r2[t + 64] + r2[t + 128] + r2[t + 192];
    atomicAdd(&g2sum[b * 64 + t], sum);
    atomicAdd(&g2ss[b * 64 + t], ss);
  }
}

__global__ __launch_bounds__(256) void gn2_norm(
    const float* __restrict__ out1, const float* __restrict__ g2sum,
    const float* __restrict__ g2ss, float* __restrict__ dout) {
  const float invS = 1.0f / 1024.0f;
  int gs = gridDim.x * blockDim.x;
  for (int i = blockIdx.x * 256 + threadIdx.x; i < 131072; i += gs) {
    float4 x = ((const float4*)out1)[i];
    int lin = i * 4;
    int f = lin & 63;
    int b = lin >> 16;
    float vals[4] = {x.x, x.y, x.z, x.w};
    float o[4];
    #pragma unroll
    for (int e = 0; e < 4; ++e) {
      float mean = g2sum[b * 64 + f + e] * invS;
      float var = g2ss[b * 64 + f + e] * invS - mean * mean;
      float rstd = rsqrtf(var + 1e-3f);
      o[e] = (vals[e] - mean) * rstd;
    }
    float4 y = {o[0], o[1], o[2], o[3]};
    ((float4*)dout)[i] = y;
  }
}

// ---------------------------------------------------------------- launch
extern "C" void kernel_launch(void* const* d_in, const int* in_sizes, int n_in,
                              void* d_out, int out_size, void* d_ws, size_t ws_size,
                              hipStream_t stream) {
  const float* qw = (const float*)d_in[0];
  const float* kw = (const float*)d_in[1];
  const float* vw = (const float*)d_in[2];
  const float* Wq = (const float*)d_in[3];
  const float* bq = (const float*)d_in[4];
  const float* Wk = (const float*)d_in[5];
  const float* bk = (const float*)d_in[6];
  const float* Wv = (const float*)d_in[7];
  const float* bv = (const float*)d_in[8];
  const float* W1 = (const float*)d_in[9];
  const float* b1 = (const float*)d_in[10];

  char* ws = (char*)d_ws;
  unsigned short* WT   = (unsigned short*)(ws);                   // 6 MB
  unsigned short* W1fT = (unsigned short*)(ws + 6291456);         // 128 KB
  unsigned short* qb   = (unsigned short*)(ws + 6422528);         // q,k,v: 3 x 16 MB bf16
  unsigned short* vT   = (unsigned short*)(ws + 56754176);        // 16 MB
  unsigned short* Abf  = (unsigned short*)(ws + 73531392);        // 48 MB (dead after qkv_gemm)
  unsigned short* en_f = (unsigned short*)(ws + 73531392);        // 16 MB bf16 (aliases Abf)
  unsigned short* enf0 = (unsigned short*)(ws + 90308608);        // 16 MB bf16
  float* out1          = (float*)(ws + 107085824);                // 2 MB
  float* gsum          = (float*)(ws + 123863040);                // 32 KB
  float* gss           = (float*)(ws + 123895808);                // 32 KB
  float* g2sum         = (float*)(ws + 123928576);                // 2 KB
  float* g2ss          = (float*)(ws + 123930624);                // 2 KB

  hipMemsetAsync(gsum, 0, 65536, stream);   // gsum + gss
  hipMemsetAsync(g2sum, 0, 4096, stream);   // g2sum + g2ss

  convert_a<<<dim3(2048, 3), 256, 0, stream>>>(qw, kw, vw, Abf);
  prep_weights<<<dim3(256, 4), 256, 0, stream>>>(Wq, Wk, Wv, W1, WT, W1fT);
  qkv_gemm<<<1536, 256, 0, stream>>>(Abf, WT, bq, bk, bv, qb);
  transpose_v<<<dim3(16, 128), 256, 0, stream>>>(qb + 2 * 8388608, vT);
  attn_kernel<<<1024, 256, 0, stream>>>(qb, qb + 8388608, vT, en_f);
  gn1_stats<<<dim3(32, 8), 256, 0, stream>>>(en_f, gsum, gss);
  gn1_norm<<<2048, 256, 0, stream>>>(en_f, gsum, gss, enf0);
  dense_kernel<<<128, 256, 0, stream>>>(enf0, W1fT, b1, out1);
  gn2_stats<<<dim3(16, 8), 256, 0, stream>>>(out1, g2sum, g2ss);
  gn2_norm<<<512, 256, 0, stream>>>(out1, g2sum, g2ss, (float*)d_out);
}